// Round 15
// baseline (53.359 us; speedup 1.0000x reference)
//
#include <hip/hip_runtime.h>

#define LOG2E 1.4426950408889634f
#define EXP2(x) __builtin_amdgcn_exp2f(x)   // bare v_exp_f32 (no ocml fixup)
#define MFMA32(a, b, c) __builtin_amdgcn_mfma_f32_32x32x16_bf16(a, b, c, 0, 0, 0)

typedef __attribute__((ext_vector_type(4)))  float f32x4;
typedef __attribute__((ext_vector_type(16))) float f32x16;
typedef __attribute__((ext_vector_type(8)))  short s16x8;
typedef __attribute__((ext_vector_type(4)))  short s16x4;
typedef __attribute__((ext_vector_type(4)))  __bf16 bf16x4;
typedef __attribute__((ext_vector_type(8)))  __bf16 bf16x8;

// B=2 S=2048 H=16 D=64, fp32 in/out.
#define SS 2048
#define HH 16
#define DD 64
#define HSZ (HH * DD)
#define BHSZ (SS * DD)  // 131072 elems per (b,h) plane

// ---- fused prep for 32x32 MFMA fragments (identical to R14, validated) ---
// Kf[bh][sub(64)][c2(4)][lane][j(8)]: lane l -> K[key=sub*32+(l&31)]
//                                              [d = c2*16 + (l>>5)*8 + j]
// Vf[bh][sub(64)][db(2)][kh(2)][lane][j(8)]: lane l ->
//     V[key = sub*32 + kh*16 + (j&3)+8*(j>>2)+4*(l>>5)][d = db*32 + (l&31)]
// (kappa(c,j) = (j&3)+8*(j>>2)+4c matches the 32x32 C-output key pattern,
//  so QK's P registers feed PV's B operand directly, slot-for-slot.)
__global__ __launch_bounds__(256) void prep_kv(const float* __restrict__ Kg,
                                               const float* __restrict__ Vg,
                                               short* __restrict__ Kf,
                                               short* __restrict__ Vf) {
  const int blk = blockIdx.x;
  if (blk < 2048) {  // ---- K part: 524,288 16B chunks
    const int idx = blk * 256 + threadIdx.x;
    const int l   = idx & 63;
    const int c2  = (idx >> 6) & 3;
    const int sub = (idx >> 8) & 63;
    const int bh  = idx >> 14;
    const int b = bh >> 4, h = bh & 15;
    const int key = (sub << 5) + (l & 31);
    const int d0  = (c2 << 4) + ((l >> 5) << 3);
    const float* src = Kg + (((size_t)b * SS + key) * HH + h) * DD + d0;
    f32x4 a = *(const f32x4*)(src);
    f32x4 b2 = *(const f32x4*)(src + 4);
    bf16x8 o;
#pragma unroll
    for (int j = 0; j < 4; ++j) {
      o[j] = (__bf16)a[j];
      o[4 + j] = (__bf16)b2[j];
    }
    *(s16x8*)(Kf + (size_t)idx * 8) = __builtin_bit_cast(s16x8, o);
  } else {           // ---- V part: 524,288 16B chunks
    const int idx = (blk - 2048) * 256 + threadIdx.x;
    const int l   = idx & 63;
    const int kh  = (idx >> 6) & 1;
    const int db  = (idx >> 7) & 1;
    const int sub = (idx >> 8) & 63;
    const int bh  = idx >> 14;
    const int b = bh >> 4, h = bh & 15;
    const int d   = (db << 5) + (l & 31);
    const int hi4 = (l >> 5) << 2;
    const float* src = Vg + (((size_t)b * SS) * HH + h) * DD + d;
    bf16x8 o;
#pragma unroll
    for (int j = 0; j < 8; ++j) {
      const int key = (sub << 5) + (kh << 4) + ((j & 3) + ((j >> 2) << 3) + hi4);
      o[j] = (__bf16)src[(size_t)key * HSZ];
    }
    *(s16x8*)(Vf + (size_t)idx * 8) = __builtin_bit_cast(s16x8, o);
  }
}

// ---- main: 32x32 MFMA + rotating K prefetch + 2-chain QK -----------------
// R14 macro-structure (1024 balanced pair-blocks x 4 waves, split-K,
// static-base softmax, raw exp2, XCD-local bh). Inner-loop chain cuts:
// (1) K fragments for subtile s+1 prefetched during s's compute (removes
//     ~200cy L2 latency from the steady-state chain);
// (2) QK computed as two independent 2-deep MFMA chains + vector add
//     (removes 2 MFMA latencies);
// (3) V loads issued at iteration top (covered by QK+exp2).
// launch_bounds(256) with NO min-waves: +32 regs of pipeline state may push
// VGPR past 128 (-> 3 waves/SIMD, mild), but never forces a spill (R7).

__device__ __forceinline__ void qtile_pass(
    const int t, const int w, const int lane,
    const float* __restrict__ Qg, const short* __restrict__ kb2,
    const short* __restrict__ vb2, float* __restrict__ Og,
    const size_t qbase, float (*lo)[33][64])
{
  const int lm31 = lane & 31;
  const int hi   = lane >> 5;
  const int n    = t + 1;                 // 32-key subtiles 0..t

  // Q fragment: q = t*32 + lm31, dims d = c2*16 + hi*8 + j, pre-scaled
  s16x8 qf[4];
  {
    const float qs = 0.125f * LOG2E;
    const float* qp = Qg + qbase + (size_t)((t << 5) + lm31) * HSZ + (hi << 3);
#pragma unroll
    for (int c2 = 0; c2 < 4; ++c2) {
      f32x4 a = *(const f32x4*)(qp + c2 * 16);
      f32x4 b2 = *(const f32x4*)(qp + c2 * 16 + 4);
      bf16x8 bv;
#pragma unroll
      for (int j = 0; j < 4; ++j) {
        bv[j] = (__bf16)(a[j] * qs);
        bv[4 + j] = (__bf16)(b2[j] * qs);
      }
      qf[c2] = __builtin_bit_cast(s16x8, bv);
    }
  }

  f32x16 oacc0 = {0,0,0,0,0,0,0,0,0,0,0,0,0,0,0,0};
  f32x16 oacc1 = {0,0,0,0,0,0,0,0,0,0,0,0,0,0,0,0};
  float lsum = 0.0f;

  // contiguous quarter [s0, e) of subtiles for this wave
  const int n4 = n >> 2, rem = n & 3;
  const int s0 = w * n4 + (w < rem ? w : rem);
  const int e  = s0 + n4 + (w < rem ? 1 : 0);

  if (s0 < e) {
    // prime the K pipeline
    const short* ka0 = kb2 + ((size_t)s0 << 11);
    s16x8 kc0 = *(const s16x8*)(ka0);
    s16x8 kc1 = *(const s16x8*)(ka0 + 512);
    s16x8 kc2 = *(const s16x8*)(ka0 + 1024);
    s16x8 kc3 = *(const s16x8*)(ka0 + 1536);

    for (int s = s0; s < e; ++s) {
      // ---- V loads for current subtile (latency covered by QK + exp2)
      const short* vpp = vb2 + ((size_t)s << 11);
      s16x8 va00 = *(const s16x8*)(vpp);          // d-blk 0, keys 0..15
      s16x8 va01 = *(const s16x8*)(vpp + 512);    // d-blk 0, keys 16..31
      s16x8 va10 = *(const s16x8*)(vpp + 1024);   // d-blk 1, keys 0..15
      s16x8 va11 = *(const s16x8*)(vpp + 1536);   // d-blk 1, keys 16..31
      // ---- next-subtile K prefetch (rotating)
      const int sn = (s + 1 < e) ? s + 1 : s;
      const short* kan = kb2 + ((size_t)sn << 11);
      s16x8 kn0 = *(const s16x8*)(kan);
      s16x8 kn1 = *(const s16x8*)(kan + 512);
      s16x8 kn2 = *(const s16x8*)(kan + 1024);
      s16x8 kn3 = *(const s16x8*)(kan + 1536);
      // ---- QK: two independent 2-deep chains, then combine
      f32x16 stA = {0,0,0,0,0,0,0,0,0,0,0,0,0,0,0,0};
      f32x16 stB = {0,0,0,0,0,0,0,0,0,0,0,0,0,0,0,0};
      stA = MFMA32(kc0, qf[0], stA);
      stB = MFMA32(kc1, qf[1], stB);
      stA = MFMA32(kc2, qf[2], stA);
      stB = MFMA32(kc3, qf[3], stB);
      f32x16 st = stA + stB;
      // st[r] = score(key = s*32 + (r&3)+8*(r>>2)+4*hi, q = t*32 + lm31)
      if (s == t) {  // diagonal subtile: causal mask
#pragma unroll
        for (int r = 0; r < 16; ++r)
          if (((r & 3) + ((r >> 2) << 3) + (hi << 2)) > lm31) st[r] = -1e30f;
      }
      // ---- static-base softmax numerator + bf16 pack (B-operand order)
      float p[16];
#pragma unroll
      for (int r = 0; r < 16; ++r) p[r] = EXP2(st[r]);
#pragma unroll
      for (int r = 0; r < 16; ++r) lsum += p[r];
      bf16x8 pb0, pb1;
#pragma unroll
      for (int r = 0; r < 8; ++r) {
        pb0[r] = (__bf16)p[r];
        pb1[r] = (__bf16)p[8 + r];
      }
      const s16x8 pf0 = __builtin_bit_cast(s16x8, pb0);
      const s16x8 pf1 = __builtin_bit_cast(s16x8, pb1);
      // ---- PV: OT[d][q] += V^T * P (A fragments match kappa slot-for-slot)
      oacc0 = MFMA32(va00, pf0, oacc0);
      oacc0 = MFMA32(va01, pf1, oacc0);
      oacc1 = MFMA32(va10, pf0, oacc1);
      oacc1 = MFMA32(va11, pf1, oacc1);
      // ---- rotate the K pipeline
      kc0 = kn0; kc1 = kn1; kc2 = kn2; kc3 = kn3;
    }
  }

  // ---- 2-stage pure-sum merge; wave 0 normalizes and stores ----
  if (w == 1 || w == 3) {
    const int slot = w >> 1;
#pragma unroll
    for (int r = 0; r < 16; ++r) {
      lo[slot][r][lane] = oacc0[r];
      lo[slot][16 + r][lane] = oacc1[r];
    }
    lo[slot][32][lane] = lsum;
  }
  __syncthreads();
  if (w == 0) {
#pragma unroll
    for (int r = 0; r < 16; ++r) {
      oacc0[r] += lo[0][r][lane];
      oacc1[r] += lo[0][16 + r][lane];
    }
    lsum += lo[0][32][lane];
  }
  if (w == 2) {
#pragma unroll
    for (int r = 0; r < 16; ++r) {
      oacc0[r] += lo[1][r][lane];
      oacc1[r] += lo[1][16 + r][lane];
    }
    lsum += lo[1][32][lane];
#pragma unroll
    for (int r = 0; r < 16; ++r) {
      lo[1][r][lane] = oacc0[r];
      lo[1][16 + r][lane] = oacc1[r];
    }
    lo[1][32][lane] = lsum;
  }
  __syncthreads();
  if (w == 0) {
#pragma unroll
    for (int r = 0; r < 16; ++r) {
      oacc0[r] += lo[1][r][lane];
      oacc1[r] += lo[1][16 + r][lane];
    }
    lsum += lo[1][32][lane];
    float l = lsum + __shfl_xor(lsum, 32);
    const float inv = 1.0f / l;
    // out[q = t*32+lm31][d = db*32 + 8*q4 + 4*hi + (0..3)]
    float* op = Og + qbase + (size_t)((t << 5) + lm31) * HSZ + (hi << 2);
#pragma unroll
    for (int db = 0; db < 2; ++db)
#pragma unroll
      for (int q4 = 0; q4 < 4; ++q4) {
        f32x4 o;
#pragma unroll
        for (int j = 0; j < 4; ++j)
          o[j] = (db ? oacc1[q4 * 4 + j] : oacc0[q4 * 4 + j]) * inv;
        *(f32x4*)(op + db * 32 + q4 * 8) = o;
      }
  }
  __syncthreads();  // protect LDS slots before the next pass republishes
}

__global__ __launch_bounds__(256) void attn_fwd15(
    const float* __restrict__ Qg, const short* __restrict__ Kf,
    const short* __restrict__ Vf, float* __restrict__ Og)
{
  __shared__ float lo[2][33][64];  // two publish slots [slot][reg][lane]

  const int tid  = threadIdx.x;
  const int lane = tid & 63;
  const int w    = tid >> 6;    // 0..3: split-K quarter

  // XCD-local mapping: id%8 = XCD (round-robin dispatch heuristic).
  const int id   = blockIdx.x;            // 0..1023
  const int xcd  = id & 7;
  const int r7   = id >> 3;               // 0..127
  const int bh   = (xcd << 2) | (r7 & 3);
  const int v    = r7 >> 2;               // 0..31
  const int tA   = 63 - v;                // heavy pass first
  const int tB   = v;                     // complementary light pass

  const size_t qbase = (size_t)(bh >> 4) * SS * HSZ + (size_t)(bh & 15) * DD;
  const short* kb2 = Kf + (size_t)bh * BHSZ + lane * 8;
  const short* vb2 = Vf + (size_t)bh * BHSZ + lane * 8;

  qtile_pass(tA, w, lane, Qg, kb2, vb2, Og, qbase, lo);
  qtile_pass(tB, w, lane, Qg, kb2, vb2, Og, qbase, lo);
}

// ---- fallback (round-1 kernel) if ws too small ---------------------------
__global__ __launch_bounds__(256) void attn_fwd(
    const float* __restrict__ Qg, const float* __restrict__ Kg,
    const float* __restrict__ Vg, float* __restrict__ Og)
{
  typedef __attribute__((ext_vector_type(4))) short s16x4v;
  const int tid  = threadIdx.x;
  const int lane = tid & 63;
  const int lm   = lane & 15;
  const int g    = lane >> 4;
  const int w    = tid >> 6;
  const int bh = blockIdx.x;
  const int b  = bh >> 4;
  const int h  = bh & 15;
  const int t  = ((gridDim.y - 1 - blockIdx.y) << 2) | w;
  const int qb = t << 4;
  const size_t base = (size_t)b * SS * HSZ + (size_t)h * DD;
  s16x4v qf[4];
  {
    const float* qp = Qg + base + (size_t)(qb + lm) * HSZ + g * 4;
    const float qs = 0.125f * LOG2E;
#pragma unroll
    for (int c = 0; c < 4; ++c) {
      f32x4 qv = *(const f32x4*)(qp + c * 16);
      bf16x4 bv;
#pragma unroll
      for (int j = 0; j < 4; ++j) bv[j] = (__bf16)(qv[j] * qs);
      qf[c] = __builtin_bit_cast(s16x4v, bv);
    }
  }
  f32x4 oacc[4] = {{0,0,0,0},{0,0,0,0},{0,0,0,0},{0,0,0,0}};
  float m = -1e30f, lsum = 0.0f;
  const float* kp = Kg + base + (size_t)lm * HSZ + g * 4;
  const float* vp = Vg + base + (size_t)(g * 4) * HSZ + lm;
  for (int kt = 0; kt <= t; ++kt) {
    const float* kpp = kp + (size_t)(kt << 4) * HSZ;
    f32x4 st = {0, 0, 0, 0};
#pragma unroll
    for (int c = 0; c < 4; ++c) {
      f32x4 kv = *(const f32x4*)(kpp + c * 16);
      bf16x4 bv;
#pragma unroll
      for (int j = 0; j < 4; ++j) bv[j] = (__bf16)kv[j];
      st = __builtin_amdgcn_mfma_f32_16x16x16bf16_1k(
               __builtin_bit_cast(s16x4v, bv), qf[c], st, 0, 0, 0);
    }
    if (kt == t) {
#pragma unroll
      for (int r = 0; r < 4; ++r)
        if (g * 4 + r > lm) st[r] = -1e30f;
    }
    float tmax = fmaxf(fmaxf(st[0], st[1]), fmaxf(st[2], st[3]));
    tmax = fmaxf(tmax, __shfl_xor(tmax, 16));
    tmax = fmaxf(tmax, __shfl_xor(tmax, 32));
    const float mnew = fmaxf(m, tmax);
    const float fsc  = exp2f(m - mnew);
    f32x4 p;
#pragma unroll
    for (int r = 0; r < 4; ++r) p[r] = exp2f(st[r] - mnew);
    float tsum = (p[0] + p[1]) + (p[2] + p[3]);
    tsum += __shfl_xor(tsum, 16);
    tsum += __shfl_xor(tsum, 32);
    lsum = lsum * fsc + tsum;
    m = mnew;
#pragma unroll
    for (int nb = 0; nb < 4; ++nb)
#pragma unroll
      for (int r = 0; r < 4; ++r) oacc[nb][r] *= fsc;
    bf16x4 pb;
#pragma unroll
    for (int r = 0; r < 4; ++r) pb[r] = (__bf16)p[r];
    const s16x4v pf = __builtin_bit_cast(s16x4v, pb);
    const float* vpp = vp + (size_t)(kt << 4) * HSZ;
#pragma unroll
    for (int nb = 0; nb < 4; ++nb) {
      bf16x4 vv;
#pragma unroll
      for (int j = 0; j < 4; ++j)
        vv[j] = (__bf16)vpp[(size_t)j * HSZ + nb * 16];
      oacc[nb] = __builtin_amdgcn_mfma_f32_16x16x16bf16_1k(
                     __builtin_bit_cast(s16x4v, vv), pf, oacc[nb], 0, 0, 0);
    }
  }
  const float inv = 1.0f / lsum;
  float* op = Og + base + (size_t)(qb + lm) * HSZ + g * 4;
#pragma unroll
  for (int nb = 0; nb < 4; ++nb) {
    f32x4 o = oacc[nb];
#pragma unroll
    for (int r = 0; r < 4; ++r) o[r] *= inv;
    *(f32x4*)(op + nb * 16) = o;
  }
}

extern "C" void kernel_launch(void* const* d_in, const int* in_sizes, int n_in,
                              void* d_out, int out_size, void* d_ws, size_t ws_size,
                              hipStream_t stream) {
  const float* q = (const float*)d_in[0];
  const float* k = (const float*)d_in[1];
  const float* v = (const float*)d_in[2];
  float* o = (float*)d_out;
  const size_t elems = (size_t)2 * HH * SS * DD;     // 4,194,304 per tensor
  const size_t need  = 2 * elems * sizeof(short);    // Kf + Vf, 16.8 MB
  if (ws_size >= need) {
    short* Kf = (short*)d_ws;
    short* Vf = Kf + elems;
    prep_kv<<<4096, 256, 0, stream>>>(k, v, Kf, Vf);
    attn_fwd15<<<1024, 256, 0, stream>>>(q, Kf, Vf, o);
  } else {
    attn_fwd<<<dim3(32, 32), 256, 0, stream>>>(q, k, v, o);
  }
}

// Round 16
// 45.442 us; speedup vs baseline: 1.1742x; 1.1742x over previous
//
#include <hip/hip_runtime.h>

#define LOG2E 1.4426950408889634f
#define EXP2(x) __builtin_amdgcn_exp2f(x)   // bare v_exp_f32 (no ocml fixup)
#define MFMA32(a, b, c) __builtin_amdgcn_mfma_f32_32x32x16_bf16(a, b, c, 0, 0, 0)

typedef __attribute__((ext_vector_type(4)))  float f32x4;
typedef __attribute__((ext_vector_type(16))) float f32x16;
typedef __attribute__((ext_vector_type(8)))  short s16x8;
typedef __attribute__((ext_vector_type(4)))  short s16x4;
typedef __attribute__((ext_vector_type(4)))  __bf16 bf16x4;
typedef __attribute__((ext_vector_type(8)))  __bf16 bf16x8;

// B=2 S=2048 H=16 D=64, fp32 in/out.
#define SS 2048
#define HH 16
#define DD 64
#define HSZ (HH * DD)
#define BHSZ (SS * DD)  // 131072 elems per (b,h) plane

// ---- prep via LDS transpose: coalesced reads AND writes ------------------
// Same output layouts as R14 (absmax-validated):
// Kf[bh][sub(64)][c2(4)][lane][j(8)]: lane l -> K[key=sub*32+(l&31)]
//                                              [d = c2*16 + (l>>5)*8 + j]
// Vf[bh][sub(64)][db(2)][kh(2)][lane][j(8)]: lane l ->
//     V[key = sub*32 + kh*16 + (j&3)+8*(j>>2)+4*(l>>5)][d = db*32 + (l&31)]
// R14's prep gathered at 4KB lane-stride (16-64 lines/instr). Here each
// block stages 128 keys x 64 dims f32 in LDS via coalesced f32x4 row reads
// (4 lines/instr), then emits fragments as fully-coalesced s16x8 writes.
// LDS row stride 65 floats: write-phase row-walks are 2-way bank (free).
__global__ __launch_bounds__(256) void prep_kv16(const float* __restrict__ Kg,
                                                 const float* __restrict__ Vg,
                                                 short* __restrict__ Kf,
                                                 short* __restrict__ Vf) {
  __shared__ float tile[128][65];
  const int tid = threadIdx.x;
  const int blk = blockIdx.x;          // 0..1023; [0,512) = K, [512,1024) = V
  const int isV = blk >> 9;
  const int local = blk & 511;
  const int bh  = local >> 4;          // 0..31
  const int grp = local & 15;          // 4-subtile group: keys grp*128..+127
  const int b = bh >> 4, h = bh & 15;
  const float* __restrict__ src = isV ? Vg : Kg;

  // ---- read phase: 128 rows x 64 f32, coalesced f32x4 ----
#pragma unroll
  for (int p = 0; p < 8; ++p) {
    const int row = p * 16 + (tid >> 4);           // 0..127
    const int d4  = (tid & 15) << 2;
    const int key = (grp << 7) + row;
    f32x4 v = *(const f32x4*)(src + (((size_t)b * SS + key) * HH + h) * DD + d4);
    tile[row][d4] = v[0];
    tile[row][d4 + 1] = v[1];
    tile[row][d4 + 2] = v[2];
    tile[row][d4 + 3] = v[3];
  }
  __syncthreads();

  // ---- write phase: 1024 coalesced s16x8 chunks per block ----
  if (!isV) {
#pragma unroll
    for (int it = 0; it < 4; ++it) {
      const int id = it * 256 + tid;
      const int l  = id & 63;
      const int c2 = (id >> 6) & 3;
      const int sl = (id >> 8) & 3;
      const int keyl = (sl << 5) + (l & 31);
      const int d0   = (c2 << 4) + ((l >> 5) << 3);
      bf16x8 o;
#pragma unroll
      for (int j = 0; j < 8; ++j) o[j] = (__bf16)tile[keyl][d0 + j];
      const size_t chunk = (((size_t)bh * 64 + ((grp << 2) + sl)) * 4 + c2) * 64 + l;
      *(s16x8*)(Kf + chunk * 8) = __builtin_bit_cast(s16x8, o);
    }
  } else {
#pragma unroll
    for (int it = 0; it < 4; ++it) {
      const int id = it * 256 + tid;
      const int l  = id & 63;
      const int kh = (id >> 6) & 1;
      const int db = (id >> 7) & 1;
      const int sl = (id >> 8) & 3;
      const int d   = (db << 5) + (l & 31);
      const int hi4 = (l >> 5) << 2;
      bf16x8 o;
#pragma unroll
      for (int j = 0; j < 8; ++j) {
        const int keyl = (sl << 5) + (kh << 4) + ((j & 3) + ((j >> 2) << 3) + hi4);
        o[j] = (__bf16)tile[keyl][d];
      }
      const size_t chunk =
          ((((size_t)bh * 64 + ((grp << 2) + sl)) * 2 + db) * 2 + kh) * 64 + l;
      *(s16x8*)(Vf + chunk * 8) = __builtin_bit_cast(s16x8, o);
    }
  }
}

// ---- main: R14 kernel, byte-identical logic (validated 48.3us best) ------
// 1024 blocks x 4 waves. Block = (bh, v): processes 32-row q-tile t=63-v
// then t=v sequentially; each pass: 4 waves split the key subtile range
// contiguously; pure-sum merge (static-base softmax); raw v_exp_f32.
// P->PV needs NO cross-lane traffic (kappa layout). XCD-local bh.
// R15 lesson: VGPR <= 64 beats in-loop prefetch (VGPR 88 halved occupancy
// via the m69 64-VGPR wave-cap step). Keep (256,4) and no pipelining.

__device__ __forceinline__ void qtile_pass(
    const int t, const int w, const int lane,
    const float* __restrict__ Qg, const short* __restrict__ kb2,
    const short* __restrict__ vb2, float* __restrict__ Og,
    const size_t qbase, float (*lo)[33][64])
{
  const int lm31 = lane & 31;
  const int hi   = lane >> 5;
  const int n    = t + 1;                 // 32-key subtiles 0..t

  // Q fragment: q = t*32 + lm31, dims d = c2*16 + hi*8 + j, pre-scaled
  s16x8 qf[4];
  {
    const float qs = 0.125f * LOG2E;
    const float* qp = Qg + qbase + (size_t)((t << 5) + lm31) * HSZ + (hi << 3);
#pragma unroll
    for (int c2 = 0; c2 < 4; ++c2) {
      f32x4 a = *(const f32x4*)(qp + c2 * 16);
      f32x4 b2 = *(const f32x4*)(qp + c2 * 16 + 4);
      bf16x8 bv;
#pragma unroll
      for (int j = 0; j < 4; ++j) {
        bv[j] = (__bf16)(a[j] * qs);
        bv[4 + j] = (__bf16)(b2[j] * qs);
      }
      qf[c2] = __builtin_bit_cast(s16x8, bv);
    }
  }

  f32x16 oacc0 = {0,0,0,0,0,0,0,0,0,0,0,0,0,0,0,0};
  f32x16 oacc1 = {0,0,0,0,0,0,0,0,0,0,0,0,0,0,0,0};
  float lsum = 0.0f;

  // contiguous quarter [s, e) of subtiles for this wave
  const int n4 = n >> 2, rem = n & 3;
  int s = w * n4 + (w < rem ? w : rem);
  const int e = s + n4 + (w < rem ? 1 : 0);

  for (; s < e; ++s) {
    const short* ka = kb2 + ((size_t)s << 11);
    // ---- QK: S^T[key][q] via 4 x mfma 32x32x16
    s16x8 k0 = *(const s16x8*)(ka);
    s16x8 k1 = *(const s16x8*)(ka + 512);
    f32x16 st = {0,0,0,0,0,0,0,0,0,0,0,0,0,0,0,0};
    st = MFMA32(k0, qf[0], st);
    st = MFMA32(k1, qf[1], st);
    s16x8 k2 = *(const s16x8*)(ka + 1024);
    s16x8 k3 = *(const s16x8*)(ka + 1536);
    st = MFMA32(k2, qf[2], st);
    st = MFMA32(k3, qf[3], st);
    // st[r] = score(key = s*32 + (r&3)+8*(r>>2)+4*hi, q = t*32 + lm31)
    if (s == t) {  // diagonal subtile: causal mask
#pragma unroll
      for (int r = 0; r < 16; ++r)
        if (((r & 3) + ((r >> 2) << 3) + (hi << 2)) > lm31) st[r] = -1e30f;
    }
    // ---- static-base softmax numerator + bf16 pack (B-operand order!)
    float p[16];
#pragma unroll
    for (int r = 0; r < 16; ++r) p[r] = EXP2(st[r]);
#pragma unroll
    for (int r = 0; r < 16; ++r) lsum += p[r];
    bf16x8 pb0, pb1;
#pragma unroll
    for (int r = 0; r < 8; ++r) {
      pb0[r] = (__bf16)p[r];
      pb1[r] = (__bf16)p[8 + r];
    }
    const s16x8 pf0 = __builtin_bit_cast(s16x8, pb0);
    const s16x8 pf1 = __builtin_bit_cast(s16x8, pb1);
    // ---- PV: OT[d][q] += V^T * P; A fragments match kappa slot-for-slot
    const short* vpp = vb2 + ((size_t)s << 11);
    s16x8 va00 = *(const s16x8*)(vpp);          // d-blk 0, keys 0..15
    s16x8 va01 = *(const s16x8*)(vpp + 512);    // d-blk 0, keys 16..31
    s16x8 va10 = *(const s16x8*)(vpp + 1024);   // d-blk 1, keys 0..15
    s16x8 va11 = *(const s16x8*)(vpp + 1536);   // d-blk 1, keys 16..31
    oacc0 = MFMA32(va00, pf0, oacc0);
    oacc0 = MFMA32(va01, pf1, oacc0);
    oacc1 = MFMA32(va10, pf0, oacc1);
    oacc1 = MFMA32(va11, pf1, oacc1);
  }

  // ---- 2-stage pure-sum merge; wave 0 normalizes and stores ----
  if (w == 1 || w == 3) {
    const int slot = w >> 1;
#pragma unroll
    for (int r = 0; r < 16; ++r) {
      lo[slot][r][lane] = oacc0[r];
      lo[slot][16 + r][lane] = oacc1[r];
    }
    lo[slot][32][lane] = lsum;
  }
  __syncthreads();
  if (w == 0) {
#pragma unroll
    for (int r = 0; r < 16; ++r) {
      oacc0[r] += lo[0][r][lane];
      oacc1[r] += lo[0][16 + r][lane];
    }
    lsum += lo[0][32][lane];
  }
  if (w == 2) {
#pragma unroll
    for (int r = 0; r < 16; ++r) {
      oacc0[r] += lo[1][r][lane];
      oacc1[r] += lo[1][16 + r][lane];
    }
    lsum += lo[1][32][lane];
#pragma unroll
    for (int r = 0; r < 16; ++r) {
      lo[1][r][lane] = oacc0[r];
      lo[1][16 + r][lane] = oacc1[r];
    }
    lo[1][32][lane] = lsum;
  }
  __syncthreads();
  if (w == 0) {
#pragma unroll
    for (int r = 0; r < 16; ++r) {
      oacc0[r] += lo[1][r][lane];
      oacc1[r] += lo[1][16 + r][lane];
    }
    lsum += lo[1][32][lane];
    float l = lsum + __shfl_xor(lsum, 32);
    const float inv = 1.0f / l;
    // out[q = t*32+lm31][d = db*32 + 8*q4 + 4*hi + (0..3)]
    float* op = Og + qbase + (size_t)((t << 5) + lm31) * HSZ + (hi << 2);
#pragma unroll
    for (int db = 0; db < 2; ++db)
#pragma unroll
      for (int q4 = 0; q4 < 4; ++q4) {
        f32x4 o;
#pragma unroll
        for (int j = 0; j < 4; ++j)
          o[j] = (db ? oacc1[q4 * 4 + j] : oacc0[q4 * 4 + j]) * inv;
        *(f32x4*)(op + db * 32 + q4 * 8) = o;
      }
  }
  __syncthreads();  // protect LDS slots before the next pass republishes
}

__global__ __launch_bounds__(256, 4) void attn_fwd16(
    const float* __restrict__ Qg, const short* __restrict__ Kf,
    const short* __restrict__ Vf, float* __restrict__ Og)
{
  __shared__ float lo[2][33][64];  // two publish slots [slot][reg][lane]

  const int tid  = threadIdx.x;
  const int lane = tid & 63;
  const int w    = tid >> 6;    // 0..3: split-K quarter

  // XCD-local mapping: id%8 = XCD (round-robin dispatch heuristic).
  const int id   = blockIdx.x;            // 0..1023
  const int xcd  = id & 7;
  const int r7   = id >> 3;               // 0..127
  const int bh   = (xcd << 2) | (r7 & 3);
  const int v    = r7 >> 2;               // 0..31
  const int tA   = 63 - v;                // heavy pass first
  const int tB   = v;                     // complementary light pass

  const size_t qbase = (size_t)(bh >> 4) * SS * HSZ + (size_t)(bh & 15) * DD;
  const short* kb2 = Kf + (size_t)bh * BHSZ + lane * 8;
  const short* vb2 = Vf + (size_t)bh * BHSZ + lane * 8;

  qtile_pass(tA, w, lane, Qg, kb2, vb2, Og, qbase, lo);
  qtile_pass(tB, w, lane, Qg, kb2, vb2, Og, qbase, lo);
}

// ---- fallback (round-1 kernel) if ws too small ---------------------------
__global__ __launch_bounds__(256) void attn_fwd(
    const float* __restrict__ Qg, const float* __restrict__ Kg,
    const float* __restrict__ Vg, float* __restrict__ Og)
{
  typedef __attribute__((ext_vector_type(4))) short s16x4v;
  const int tid  = threadIdx.x;
  const int lane = tid & 63;
  const int lm   = lane & 15;
  const int g    = lane >> 4;
  const int w    = tid >> 6;
  const int bh = blockIdx.x;
  const int b  = bh >> 4;
  const int h  = bh & 15;
  const int t  = ((gridDim.y - 1 - blockIdx.y) << 2) | w;
  const int qb = t << 4;
  const size_t base = (size_t)b * SS * HSZ + (size_t)h * DD;
  s16x4v qf[4];
  {
    const float* qp = Qg + base + (size_t)(qb + lm) * HSZ + g * 4;
    const float qs = 0.125f * LOG2E;
#pragma unroll
    for (int c = 0; c < 4; ++c) {
      f32x4 qv = *(const f32x4*)(qp + c * 16);
      bf16x4 bv;
#pragma unroll
      for (int j = 0; j < 4; ++j) bv[j] = (__bf16)(qv[j] * qs);
      qf[c] = __builtin_bit_cast(s16x4v, bv);
    }
  }
  f32x4 oacc[4] = {{0,0,0,0},{0,0,0,0},{0,0,0,0},{0,0,0,0}};
  float m = -1e30f, lsum = 0.0f;
  const float* kp = Kg + base + (size_t)lm * HSZ + g * 4;
  const float* vp = Vg + base + (size_t)(g * 4) * HSZ + lm;
  for (int kt = 0; kt <= t; ++kt) {
    const float* kpp = kp + (size_t)(kt << 4) * HSZ;
    f32x4 st = {0, 0, 0, 0};
#pragma unroll
    for (int c = 0; c < 4; ++c) {
      f32x4 kv = *(const f32x4*)(kpp + c * 16);
      bf16x4 bv;
#pragma unroll
      for (int j = 0; j < 4; ++j) bv[j] = (__bf16)kv[j];
      st = __builtin_amdgcn_mfma_f32_16x16x16bf16_1k(
               __builtin_bit_cast(s16x4v, bv), qf[c], st, 0, 0, 0);
    }
    if (kt == t) {
#pragma unroll
      for (int r = 0; r < 4; ++r)
        if (g * 4 + r > lm) st[r] = -1e30f;
    }
    float tmax = fmaxf(fmaxf(st[0], st[1]), fmaxf(st[2], st[3]));
    tmax = fmaxf(tmax, __shfl_xor(tmax, 16));
    tmax = fmaxf(tmax, __shfl_xor(tmax, 32));
    const float mnew = fmaxf(m, tmax);
    const float fsc  = exp2f(m - mnew);
    f32x4 p;
#pragma unroll
    for (int r = 0; r < 4; ++r) p[r] = exp2f(st[r] - mnew);
    float tsum = (p[0] + p[1]) + (p[2] + p[3]);
    tsum += __shfl_xor(tsum, 16);
    tsum += __shfl_xor(tsum, 32);
    lsum = lsum * fsc + tsum;
    m = mnew;
#pragma unroll
    for (int nb = 0; nb < 4; ++nb)
#pragma unroll
      for (int r = 0; r < 4; ++r) oacc[nb][r] *= fsc;
    bf16x4 pb;
#pragma unroll
    for (int r = 0; r < 4; ++r) pb[r] = (__bf16)p[r];
    const s16x4v pf = __builtin_bit_cast(s16x4v, pb);
    const float* vpp = vp + (size_t)(kt << 4) * HSZ;
#pragma unroll
    for (int nb = 0; nb < 4; ++nb) {
      bf16x4 vv;
#pragma unroll
      for (int j = 0; j < 4; ++j)
        vv[j] = (__bf16)vpp[(size_t)j * HSZ + nb * 16];
      oacc[nb] = __builtin_amdgcn_mfma_f32_16x16x16bf16_1k(
                     __builtin_bit_cast(s16x4v, vv), pf, oacc[nb], 0, 0, 0);
    }
  }
  const float inv = 1.0f / lsum;
  float* op = Og + base + (size_t)(qb + lm) * HSZ + g * 4;
#pragma unroll
  for (int nb = 0; nb < 4; ++nb) {
    f32x4 o = oacc[nb];
#pragma unroll
    for (int r = 0; r < 4; ++r) o[r] *= inv;
    *(f32x4*)(op + nb * 16) = o;
  }
}

extern "C" void kernel_launch(void* const* d_in, const int* in_sizes, int n_in,
                              void* d_out, int out_size, void* d_ws, size_t ws_size,
                              hipStream_t stream) {
  const float* q = (const float*)d_in[0];
  const float* k = (const float*)d_in[1];
  const float* v = (const float*)d_in[2];
  float* o = (float*)d_out;
  const size_t elems = (size_t)2 * HH * SS * DD;     // 4,194,304 per tensor
  const size_t need  = 2 * elems * sizeof(short);    // Kf + Vf, 16.8 MB
  if (ws_size >= need) {
    short* Kf = (short*)d_ws;
    short* Vf = Kf + elems;
    prep_kv16<<<1024, 256, 0, stream>>>(k, v, Kf, Vf);
    attn_fwd16<<<1024, 256, 0, stream>>>(q, Kf, Vf, o);
  } else {
    attn_fwd<<<dim3(32, 32), 256, 0, stream>>>(q, k, v, o);
  }
}

// Round 17
// 44.841 us; speedup vs baseline: 1.1900x; 1.0134x over previous
//
#include <hip/hip_runtime.h>

#define LOG2E 1.4426950408889634f
#define EXP2(x) __builtin_amdgcn_exp2f(x)   // bare v_exp_f32 (no ocml fixup)
#define MFMA32(a, b, c) __builtin_amdgcn_mfma_f32_32x32x16_bf16(a, b, c, 0, 0, 0)

typedef __attribute__((ext_vector_type(4)))  float f32x4;
typedef __attribute__((ext_vector_type(16))) float f32x16;
typedef __attribute__((ext_vector_type(8)))  short s16x8;
typedef __attribute__((ext_vector_type(4)))  short s16x4;
typedef __attribute__((ext_vector_type(4)))  __bf16 bf16x4;
typedef __attribute__((ext_vector_type(8)))  __bf16 bf16x8;

// B=2 S=2048 H=16 D=64, fp32 in/out.
#define SS 2048
#define HH 16
#define DD 64
#define HSZ (HH * DD)
#define BHSZ (SS * DD)  // 131072 elems per (b,h) plane

// ---- prep via LDS transpose (R16, validated): coalesced reads + writes ---
// Kf[bh][sub(64)][c2(4)][lane][j(8)]: lane l -> K[key=sub*32+(l&31)]
//                                              [d = c2*16 + (l>>5)*8 + j]
// Vf[bh][sub(64)][db(2)][kh(2)][lane][j(8)]: lane l ->
//     V[key = sub*32 + kh*16 + (j&3)+8*(j>>2)+4*(l>>5)][d = db*32 + (l&31)]
__global__ __launch_bounds__(256) void prep_kv16(const float* __restrict__ Kg,
                                                 const float* __restrict__ Vg,
                                                 short* __restrict__ Kf,
                                                 short* __restrict__ Vf) {
  __shared__ float tile[128][65];
  const int tid = threadIdx.x;
  const int blk = blockIdx.x;          // 0..1023; [0,512) = K, [512,1024) = V
  const int isV = blk >> 9;
  const int local = blk & 511;
  const int bh  = local >> 4;          // 0..31
  const int grp = local & 15;          // 4-subtile group: keys grp*128..+127
  const int b = bh >> 4, h = bh & 15;
  const float* __restrict__ src = isV ? Vg : Kg;

#pragma unroll
  for (int p = 0; p < 8; ++p) {
    const int row = p * 16 + (tid >> 4);           // 0..127
    const int d4  = (tid & 15) << 2;
    const int key = (grp << 7) + row;
    f32x4 v = *(const f32x4*)(src + (((size_t)b * SS + key) * HH + h) * DD + d4);
    tile[row][d4] = v[0];
    tile[row][d4 + 1] = v[1];
    tile[row][d4 + 2] = v[2];
    tile[row][d4 + 3] = v[3];
  }
  __syncthreads();

  if (!isV) {
#pragma unroll
    for (int it = 0; it < 4; ++it) {
      const int id = it * 256 + tid;
      const int l  = id & 63;
      const int c2 = (id >> 6) & 3;
      const int sl = (id >> 8) & 3;
      const int keyl = (sl << 5) + (l & 31);
      const int d0   = (c2 << 4) + ((l >> 5) << 3);
      bf16x8 o;
#pragma unroll
      for (int j = 0; j < 8; ++j) o[j] = (__bf16)tile[keyl][d0 + j];
      const size_t chunk = (((size_t)bh * 64 + ((grp << 2) + sl)) * 4 + c2) * 64 + l;
      *(s16x8*)(Kf + chunk * 8) = __builtin_bit_cast(s16x8, o);
    }
  } else {
#pragma unroll
    for (int it = 0; it < 4; ++it) {
      const int id = it * 256 + tid;
      const int l  = id & 63;
      const int kh = (id >> 6) & 1;
      const int db = (id >> 7) & 1;
      const int sl = (id >> 8) & 3;
      const int d   = (db << 5) + (l & 31);
      const int hi4 = (l >> 5) << 2;
      bf16x8 o;
#pragma unroll
      for (int j = 0; j < 8; ++j) {
        const int keyl = (sl << 5) + (kh << 4) + ((j & 3) + ((j >> 2) << 3) + hi4);
        o[j] = (__bf16)tile[keyl][d];
      }
      const size_t chunk =
          ((((size_t)bh * 64 + ((grp << 2) + sl)) * 2 + db) * 2 + kh) * 64 + l;
      *(s16x8*)(Vf + chunk * 8) = __builtin_bit_cast(s16x8, o);
    }
  }
}

// ---- main: R14 body, single tile per block, 2048 blocks -------------------
// 2048 blocks x 4 waves; block = (bh, t) one 32-row q-tile, 4-way split-K,
// single pure-sum merge. 8192 waves = 32 waves/CU nominal supply (R12-R16's
// pairing capped supply at 16/CU = 50% occupancy ceiling; with 8 block
// slots/CU, heavy-first LPT packs the unequal blocks). Heavy-first,
// XCD-local bh. Static-base softmax, raw v_exp_f32, kappa V layout (no
// cross-lane P traffic). lsum via depth-4 tree (was 16-deep serial chain).
// R15 lesson kept: no register pipelining; VGPR stays ~64.

__global__ __launch_bounds__(256, 4) void attn_fwd17(
    const float* __restrict__ Qg, const short* __restrict__ Kf,
    const short* __restrict__ Vf, float* __restrict__ Og)
{
  __shared__ float lo[2][33][64];  // two publish slots [slot][reg][lane]

  const int tid  = threadIdx.x;
  const int lane = tid & 63;
  const int w    = tid >> 6;    // 0..3: split-K quarter
  const int lm31 = lane & 31;
  const int hi   = lane >> 5;

  // XCD-local mapping: id%8 = XCD (round-robin dispatch heuristic).
  const int id   = blockIdx.x;            // 0..2047
  const int xcd  = id & 7;
  const int r8   = id >> 3;               // 0..255
  const int bh   = (xcd << 2) | (r8 & 3);
  const int t    = 63 - (r8 >> 2);        // q-tile 63..0, heavy-first
  const int n    = t + 1;                 // 32-key subtiles 0..t

  const size_t qbase = (size_t)(bh >> 4) * SS * HSZ + (size_t)(bh & 15) * DD;
  const short* kb2 = Kf + (size_t)bh * BHSZ + lane * 8;
  const short* vb2 = Vf + (size_t)bh * BHSZ + lane * 8;

  // Q fragment: q = t*32 + lm31, dims d = c2*16 + hi*8 + j, pre-scaled
  s16x8 qf[4];
  {
    const float qs = 0.125f * LOG2E;
    const float* qp = Qg + qbase + (size_t)((t << 5) + lm31) * HSZ + (hi << 3);
#pragma unroll
    for (int c2 = 0; c2 < 4; ++c2) {
      f32x4 a = *(const f32x4*)(qp + c2 * 16);
      f32x4 b2 = *(const f32x4*)(qp + c2 * 16 + 4);
      bf16x8 bv;
#pragma unroll
      for (int j = 0; j < 4; ++j) {
        bv[j] = (__bf16)(a[j] * qs);
        bv[4 + j] = (__bf16)(b2[j] * qs);
      }
      qf[c2] = __builtin_bit_cast(s16x8, bv);
    }
  }

  f32x16 oacc0 = {0,0,0,0,0,0,0,0,0,0,0,0,0,0,0,0};
  f32x16 oacc1 = {0,0,0,0,0,0,0,0,0,0,0,0,0,0,0,0};
  float lsum = 0.0f;

  // contiguous quarter [s, e) of subtiles for this wave
  const int n4 = n >> 2, rem = n & 3;
  int s = w * n4 + (w < rem ? w : rem);
  const int e = s + n4 + (w < rem ? 1 : 0);

  for (; s < e; ++s) {
    const short* ka = kb2 + ((size_t)s << 11);
    // ---- QK: S^T[key][q] via 4 x mfma 32x32x16
    s16x8 k0 = *(const s16x8*)(ka);
    s16x8 k1 = *(const s16x8*)(ka + 512);
    f32x16 st = {0,0,0,0,0,0,0,0,0,0,0,0,0,0,0,0};
    st = MFMA32(k0, qf[0], st);
    st = MFMA32(k1, qf[1], st);
    s16x8 k2 = *(const s16x8*)(ka + 1024);
    s16x8 k3 = *(const s16x8*)(ka + 1536);
    st = MFMA32(k2, qf[2], st);
    st = MFMA32(k3, qf[3], st);
    // st[r] = score(key = s*32 + (r&3)+8*(r>>2)+4*hi, q = t*32 + lm31)
    if (s == t) {  // diagonal subtile: causal mask
#pragma unroll
      for (int r = 0; r < 16; ++r)
        if (((r & 3) + ((r >> 2) << 3) + (hi << 2)) > lm31) st[r] = -1e30f;
    }
    // ---- static-base softmax numerator + bf16 pack (B-operand order!)
    float p[16];
#pragma unroll
    for (int r = 0; r < 16; ++r) p[r] = EXP2(st[r]);
    {  // depth-4 tree sum (was a 16-deep serial dependence chain)
      const float s0 = (p[0] + p[1]) + (p[2] + p[3]);
      const float s1 = (p[4] + p[5]) + (p[6] + p[7]);
      const float s2 = (p[8] + p[9]) + (p[10] + p[11]);
      const float s3 = (p[12] + p[13]) + (p[14] + p[15]);
      lsum += (s0 + s1) + (s2 + s3);
    }
    bf16x8 pb0, pb1;
#pragma unroll
    for (int r = 0; r < 8; ++r) {
      pb0[r] = (__bf16)p[r];
      pb1[r] = (__bf16)p[8 + r];
    }
    const s16x8 pf0 = __builtin_bit_cast(s16x8, pb0);
    const s16x8 pf1 = __builtin_bit_cast(s16x8, pb1);
    // ---- PV: OT[d][q] += V^T * P; A fragments match kappa slot-for-slot
    const short* vpp = vb2 + ((size_t)s << 11);
    s16x8 va00 = *(const s16x8*)(vpp);          // d-blk 0, keys 0..15
    s16x8 va01 = *(const s16x8*)(vpp + 512);    // d-blk 0, keys 16..31
    s16x8 va10 = *(const s16x8*)(vpp + 1024);   // d-blk 1, keys 0..15
    s16x8 va11 = *(const s16x8*)(vpp + 1536);   // d-blk 1, keys 16..31
    oacc0 = MFMA32(va00, pf0, oacc0);
    oacc0 = MFMA32(va01, pf1, oacc0);
    oacc1 = MFMA32(va10, pf0, oacc1);
    oacc1 = MFMA32(va11, pf1, oacc1);
  }

  // ---- 2-stage pure-sum merge; wave 0 normalizes and stores ----
  if (w == 1 || w == 3) {
    const int slot = w >> 1;
#pragma unroll
    for (int r = 0; r < 16; ++r) {
      lo[slot][r][lane] = oacc0[r];
      lo[slot][16 + r][lane] = oacc1[r];
    }
    lo[slot][32][lane] = lsum;
  }
  __syncthreads();
  if (w == 0) {
#pragma unroll
    for (int r = 0; r < 16; ++r) {
      oacc0[r] += lo[0][r][lane];
      oacc1[r] += lo[0][16 + r][lane];
    }
    lsum += lo[0][32][lane];
  }
  if (w == 2) {
#pragma unroll
    for (int r = 0; r < 16; ++r) {
      oacc0[r] += lo[1][r][lane];
      oacc1[r] += lo[1][16 + r][lane];
    }
    lsum += lo[1][32][lane];
#pragma unroll
    for (int r = 0; r < 16; ++r) {
      lo[1][r][lane] = oacc0[r];
      lo[1][16 + r][lane] = oacc1[r];
    }
    lo[1][32][lane] = lsum;
  }
  __syncthreads();
  if (w == 0) {
#pragma unroll
    for (int r = 0; r < 16; ++r) {
      oacc0[r] += lo[1][r][lane];
      oacc1[r] += lo[1][16 + r][lane];
    }
    lsum += lo[1][32][lane];
    float l = lsum + __shfl_xor(lsum, 32);
    const float inv = 1.0f / l;
    // out[q = t*32+lm31][d = db*32 + 8*q4 + 4*hi + (0..3)]
    float* op = Og + qbase + (size_t)((t << 5) + lm31) * HSZ + (hi << 2);
#pragma unroll
    for (int db = 0; db < 2; ++db)
#pragma unroll
      for (int q4 = 0; q4 < 4; ++q4) {
        f32x4 o;
#pragma unroll
        for (int j = 0; j < 4; ++j)
          o[j] = (db ? oacc1[q4 * 4 + j] : oacc0[q4 * 4 + j]) * inv;
        *(f32x4*)(op + db * 32 + q4 * 8) = o;
      }
  }
}

// ---- fallback (round-1 kernel) if ws too small ---------------------------
__global__ __launch_bounds__(256) void attn_fwd(
    const float* __restrict__ Qg, const float* __restrict__ Kg,
    const float* __restrict__ Vg, float* __restrict__ Og)
{
  typedef __attribute__((ext_vector_type(4))) short s16x4v;
  const int tid  = threadIdx.x;
  const int lane = tid & 63;
  const int lm   = lane & 15;
  const int g    = lane >> 4;
  const int w    = tid >> 6;
  const int bh = blockIdx.x;
  const int b  = bh >> 4;
  const int h  = bh & 15;
  const int t  = ((gridDim.y - 1 - blockIdx.y) << 2) | w;
  const int qb = t << 4;
  const size_t base = (size_t)b * SS * HSZ + (size_t)h * DD;
  s16x4v qf[4];
  {
    const float* qp = Qg + base + (size_t)(qb + lm) * HSZ + g * 4;
    const float qs = 0.125f * LOG2E;
#pragma unroll
    for (int c = 0; c < 4; ++c) {
      f32x4 qv = *(const f32x4*)(qp + c * 16);
      bf16x4 bv;
#pragma unroll
      for (int j = 0; j < 4; ++j) bv[j] = (__bf16)(qv[j] * qs);
      qf[c] = __builtin_bit_cast(s16x4v, bv);
    }
  }
  f32x4 oacc[4] = {{0,0,0,0},{0,0,0,0},{0,0,0,0},{0,0,0,0}};
  float m = -1e30f, lsum = 0.0f;
  const float* kp = Kg + base + (size_t)lm * HSZ + g * 4;
  const float* vp = Vg + base + (size_t)(g * 4) * HSZ + lm;
  for (int kt = 0; kt <= t; ++kt) {
    const float* kpp = kp + (size_t)(kt << 4) * HSZ;
    f32x4 st = {0, 0, 0, 0};
#pragma unroll
    for (int c = 0; c < 4; ++c) {
      f32x4 kv = *(const f32x4*)(kpp + c * 16);
      bf16x4 bv;
#pragma unroll
      for (int j = 0; j < 4; ++j) bv[j] = (__bf16)kv[j];
      st = __builtin_amdgcn_mfma_f32_16x16x16bf16_1k(
               __builtin_bit_cast(s16x4v, bv), qf[c], st, 0, 0, 0);
    }
    if (kt == t) {
#pragma unroll
      for (int r = 0; r < 4; ++r)
        if (g * 4 + r > lm) st[r] = -1e30f;
    }
    float tmax = fmaxf(fmaxf(st[0], st[1]), fmaxf(st[2], st[3]));
    tmax = fmaxf(tmax, __shfl_xor(tmax, 16));
    tmax = fmaxf(tmax, __shfl_xor(tmax, 32));
    const float mnew = fmaxf(m, tmax);
    const float fsc  = exp2f(m - mnew);
    f32x4 p;
#pragma unroll
    for (int r = 0; r < 4; ++r) p[r] = exp2f(st[r] - mnew);
    float tsum = (p[0] + p[1]) + (p[2] + p[3]);
    tsum += __shfl_xor(tsum, 16);
    tsum += __shfl_xor(tsum, 32);
    lsum = lsum * fsc + tsum;
    m = mnew;
#pragma unroll
    for (int nb = 0; nb < 4; ++nb)
#pragma unroll
      for (int r = 0; r < 4; ++r) oacc[nb][r] *= fsc;
    bf16x4 pb;
#pragma unroll
    for (int r = 0; r < 4; ++r) pb[r] = (__bf16)p[r];
    const s16x4v pf = __builtin_bit_cast(s16x4v, pb);
    const float* vpp = vp + (size_t)(kt << 4) * HSZ;
#pragma unroll
    for (int nb = 0; nb < 4; ++nb) {
      bf16x4 vv;
#pragma unroll
      for (int j = 0; j < 4; ++j)
        vv[j] = (__bf16)vpp[(size_t)j * HSZ + nb * 16];
      oacc[nb] = __builtin_amdgcn_mfma_f32_16x16x16bf16_1k(
                     __builtin_bit_cast(s16x4v, vv), pf, oacc[nb], 0, 0, 0);
    }
  }
  const float inv = 1.0f / lsum;
  float* op = Og + base + (size_t)(qb + lm) * HSZ + g * 4;
#pragma unroll
  for (int nb = 0; nb < 4; ++nb) {
    f32x4 o = oacc[nb];
#pragma unroll
    for (int r = 0; r < 4; ++r) o[r] *= inv;
    *(f32x4*)(op + nb * 16) = o;
  }
}

extern "C" void kernel_launch(void* const* d_in, const int* in_sizes, int n_in,
                              void* d_out, int out_size, void* d_ws, size_t ws_size,
                              hipStream_t stream) {
  const float* q = (const float*)d_in[0];
  const float* k = (const float*)d_in[1];
  const float* v = (const float*)d_in[2];
  float* o = (float*)d_out;
  const size_t elems = (size_t)2 * HH * SS * DD;     // 4,194,304 per tensor
  const size_t need  = 2 * elems * sizeof(short);    // Kf + Vf, 16.8 MB
  if (ws_size >= need) {
    short* Kf = (short*)d_ws;
    short* Vf = Kf + elems;
    prep_kv16<<<1024, 256, 0, stream>>>(k, v, Kf, Vf);
    attn_fwd17<<<2048, 256, 0, stream>>>(q, Kf, Vf, o);
  } else {
    attn_fwd<<<dim3(32, 32), 256, 0, stream>>>(q, k, v, o);
  }
}